// Round 6
// baseline (35400.006 us; speedup 1.0000x reference)
//
#include <hip/hip_runtime.h>

// Seq2Seq LSTM (E=256,H=512,B=1024,S=128,T=128). FP32 inputs, FP32 OUTPUT
// (round-6 theory: harness reads d_out as fp32, matching the reference's
// fp32 return; earlier rounds wrote bf16 halfwords -> pseudo-float garbage).
// Pure fp32 VALU implementation (known-consistent across rounds 2-5).

typedef unsigned short u16;

__device__ __forceinline__ float sigm(float x) { return 1.0f / (1.0f + expf(-x)); }

// ---------------------------------------------------------------- prep ------
// Combined interleaved bias bc[4j+g] = bih[g*512+j] + bhh[g*512+j];
// fwT (512x128) = fc_w^T; fcb copy; zero h0/c; zero out[:,0,:].
__global__ __launch_bounds__(256) void prep_v(
    const float* __restrict__ e_bih, const float* __restrict__ e_bhh,
    const float* __restrict__ d_bih, const float* __restrict__ d_bhh,
    const float* __restrict__ fc_w, const float* __restrict__ fc_b,
    float* __restrict__ bcE, float* __restrict__ bcD,
    float* __restrict__ fwT, float* __restrict__ fcb,
    float* __restrict__ h0, float* __restrict__ c, float* __restrict__ out) {
  int idx0 = blockIdx.x * blockDim.x + threadIdx.x;
  int stride = gridDim.x * blockDim.x;
  for (int i = idx0; i < 2048; i += stride) {
    int j = i >> 2, g = i & 3, orig = g * 512 + j;  // gate order i,f,g,o
    bcE[i] = e_bih[orig] + e_bhh[orig];
    bcD[i] = d_bih[orig] + d_bhh[orig];
  }
  for (int i = idx0; i < 128 * 512; i += stride) {
    int v = i >> 9, k = i & 511;           // fc_w[v][k]
    fwT[k * 128 + v] = fc_w[i];
  }
  for (int i = idx0; i < 128; i += stride) fcb[i] = fc_b[i];
  for (int i = idx0; i < 1024 * 512; i += stride) { h0[i] = 0.0f; c[i] = 0.0f; }
  for (int i = idx0; i < 1024 * 128; i += stride)
    out[(i >> 7) * 16384 + (i & 127)] = 0.0f;  // out[:,0,:] = 0
}

// ------------------------------------------------------------ lstm step -----
// grid (32,16): blockIdx.x -> n0 = bx*64 (interleaved gate cols = 16 units),
// blockIdx.y -> m0 = by*64 (batch). 256 threads.
// Thread (r = tid&63, uq = tid>>6) computes gates for batch row m0+r,
// units gu = n0/4 + uq*4 .. +4 (16 interleaved gate columns), then the cell.
__global__ __launch_bounds__(256) void lstm_step_v(
    const float* __restrict__ embp,  // (V,256) fp32
    const int* __restrict__ idx,     // (B,128)
    int t,
    const float* __restrict__ wih,   // (2048,256) fp32, reference layout
    const float* __restrict__ whh,   // (2048,512) fp32, reference layout
    const float* __restrict__ bc,    // (2048) fp32 interleaved
    const float* __restrict__ h_in,  // (1024,512) fp32
    float* __restrict__ h_out,       // (1024,512) fp32
    float* __restrict__ c) {         // (1024,512) fp32
  __shared__ float smA[64 * 33];   // A tile 64x32, stride 33 (conflict-free)
  __shared__ float smB[64 * 36];   // B tile 64x32, stride 36 (16B-aligned rows)
  __shared__ int sidx[64];
  const int tid = threadIdx.x;
  const int m0 = blockIdx.y * 64;
  const int n0 = blockIdx.x * 64;

  if (tid < 64) sidx[tid] = idx[(m0 + tid) * 128 + t];
  __syncthreads();

  // staging assignment: row rs = tid>>2, 8 elements at qo = (tid&3)*8
  const int rs = tid >> 2;
  const int qo = (tid & 3) * 8;
  const float* aEmb = embp + sidx[rs] * 256 + qo;
  const float* aH = h_in + (m0 + rs) * 512 + qo;
  // B source: interleaved row rr = n0+rs -> gate g of unit j, orig row g*512+j
  const int rr = n0 + rs;
  const int jj = rr >> 2, gg_ = rr & 3;
  const int orig = gg_ * 512 + jj;
  const float* wiB = wih + orig * 256 + qo;
  const float* whB = whh + orig * 512 + qo;

  const int r = tid & 63;
  const int uq = tid >> 6;
  const float* brow = &smB[(uq * 16) * 36];

  float acc[16];
#pragma unroll
  for (int j = 0; j < 16; ++j) acc[j] = 0.0f;

  for (int kk = 0; kk < 24; ++kk) {
    const int k0 = kk * 32;
    const float* asrc = (k0 < 256) ? (aEmb + k0) : (aH + (k0 - 256));
    const float* bsrc = (k0 < 256) ? (wiB + k0) : (whB + (k0 - 256));
    float4 ua = *(const float4*)asrc;
    float4 ua2 = *(const float4*)(asrc + 4);
    float4 ub = *(const float4*)bsrc;
    float4 ub2 = *(const float4*)(bsrc + 4);
    float* da = &smA[rs * 33 + qo];
    da[0] = ua.x; da[1] = ua.y; da[2] = ua.z; da[3] = ua.w;
    da[4] = ua2.x; da[5] = ua2.y; da[6] = ua2.z; da[7] = ua2.w;
    *(float4*)&smB[rs * 36 + qo] = ub;
    *(float4*)&smB[rs * 36 + qo + 4] = ub2;
    __syncthreads();

    const float* ar = &smA[r * 33];
#pragma unroll
    for (int k4 = 0; k4 < 8; ++k4) {
      float a0 = ar[k4 * 4 + 0];
      float a1 = ar[k4 * 4 + 1];
      float a2 = ar[k4 * 4 + 2];
      float a3 = ar[k4 * 4 + 3];
#pragma unroll
      for (int j = 0; j < 16; ++j) {
        float4 b = *(const float4*)&brow[j * 36 + k4 * 4];
        acc[j] += a0 * b.x + a1 * b.y + a2 * b.z + a3 * b.w;
      }
    }
    __syncthreads();
  }

  // fused LSTM cell: 4 units per thread
  const int gb = m0 + r;
#pragma unroll
  for (int uu = 0; uu < 4; ++uu) {
    const int j0 = uu * 4;
    const int bb = n0 + uq * 16 + j0;
    float gi = acc[j0 + 0] + bc[bb + 0];
    float gf = acc[j0 + 1] + bc[bb + 1];
    float gG = acc[j0 + 2] + bc[bb + 2];
    float go = acc[j0 + 3] + bc[bb + 3];
    const int gu = (n0 >> 2) + uq * 4 + uu;
    const int ci = gb * 512 + gu;
    float cold = c[ci];
    float cn = sigm(gf) * cold + sigm(gi) * tanhf(gG);
    c[ci] = cn;
    h_out[ci] = sigm(go) * tanhf(cn);
  }
}

// --------------------------------------------------------------- fc step ----
// out[:, t+1, :] = h @ fc_w^T + fc_b. grid (128), 256 thr; block = 8 batch
// rows; thread (v = tid&127, half = tid>>7) computes half-K dots for 8 rows.
__global__ __launch_bounds__(256) void fc_step_v(
    const float* __restrict__ h,    // (1024,512) fp32
    const float* __restrict__ fwT,  // (512,128) fp32 = fc_w^T
    const float* __restrict__ fcb,  // (128) fp32
    float* __restrict__ out, int t) {
  __shared__ float smH[4096];  // 8 rows x 512, also reused as reduce scratch
  const int tid = threadIdx.x;
  const int b0 = blockIdx.x * 8;
  const float* hb = h + b0 * 512;
#pragma unroll
  for (int m = 0; m < 4; ++m) {
    int o = m * 1024 + tid * 4;
    *(float4*)&smH[o] = *(const float4*)(hb + o);
  }
  __syncthreads();

  const int v = tid & 127;
  const int half = tid >> 7;
  float acc[8];
#pragma unroll
  for (int r0 = 0; r0 < 8; ++r0) acc[r0] = 0.0f;
  const int kbase = half * 256;
  for (int k = kbase; k < kbase + 256; ++k) {
    float w = fwT[k * 128 + v];
#pragma unroll
    for (int r0 = 0; r0 < 8; ++r0) acc[r0] += smH[r0 * 512 + k] * w;
  }
  __syncthreads();  // done reading smH; reuse as reduction scratch
  float* red = smH;
#pragma unroll
  for (int r0 = 0; r0 < 8; ++r0) red[half * 1024 + r0 * 128 + v] = acc[r0];
  __syncthreads();
  if (half == 0) {
    float bias = fcb[v];
#pragma unroll
    for (int r0 = 0; r0 < 8; ++r0) {
      float sum = red[r0 * 128 + v] + red[1024 + r0 * 128 + v] + bias;
      out[(b0 + r0) * 16384 + (t + 1) * 128 + v] = sum;
    }
  }
}

// ---------------------------------------------------------------- launch ----
extern "C" void kernel_launch(void* const* d_in, const int* in_sizes, int n_in,
                              void* d_out, int out_size, void* d_ws, size_t ws_size,
                              hipStream_t stream) {
  const int* src = (const int*)d_in[0];
  const int* tgt = (const int*)d_in[1];
  const float* emb = (const float*)d_in[2];
  const float* dec_emb = (const float*)d_in[3];
  const float* e_wih = (const float*)d_in[4];
  const float* e_whh = (const float*)d_in[5];
  const float* e_bih = (const float*)d_in[6];
  const float* e_bhh = (const float*)d_in[7];
  const float* d_wih = (const float*)d_in[8];
  const float* d_whh = (const float*)d_in[9];
  const float* d_bih = (const float*)d_in[10];
  const float* d_bhh = (const float*)d_in[11];
  const float* fc_w = (const float*)d_in[12];
  const float* fc_b = (const float*)d_in[13];
  float* out = (float*)d_out;

  char* ws = (char*)d_ws;
  float* bcE = (float*)(ws + 0);          // 8,192 B
  float* bcD = (float*)(ws + 8192);       // 8,192 B
  float* fwT = (float*)(ws + 16384);      // 262,144 B
  float* fcb = (float*)(ws + 278528);     // 512 B
  float* h0f = (float*)(ws + 279040);     // 2,097,152 B
  float* h1f = (float*)(ws + 2376192);    // 2,097,152 B
  float* cbuf = (float*)(ws + 4473344);   // 2,097,152 B  (total ~6.6 MB)

  prep_v<<<256, 256, 0, stream>>>(e_bih, e_bhh, d_bih, d_bhh, fc_w, fc_b,
                                  bcE, bcD, fwT, fcb, h0f, cbuf, out);

  dim3 gstep(32, 16);
  const float* hin = h0f;
  float* hout = h1f;
  for (int t = 0; t < 128; ++t) {
    lstm_step_v<<<gstep, 256, 0, stream>>>(emb, src, t, e_wih, e_whh, bcE,
                                           hin, hout, cbuf);
    const float* tmp = hout; hout = (float*)hin; hin = tmp;
  }
  for (int t = 0; t < 127; ++t) {
    lstm_step_v<<<gstep, 256, 0, stream>>>(dec_emb, tgt, t, d_wih, d_whh, bcD,
                                           hin, hout, cbuf);
    const float* tmp = hout; hout = (float*)hin; hin = tmp;
    fc_step_v<<<128, 256, 0, stream>>>(hin, fwT, fcb, out, t);
  }
}

// Round 7
// 14127.328 us; speedup vs baseline: 2.5058x; 2.5058x over previous
//
#include <hip/hip_runtime.h>

// Seq2Seq LSTM (E=256,H=512,B=1024,S=128,T=128). FP32 inputs, FP32 output
// (verified round 6). Round 7: gates GEMM on MFMA bf16 with 3-term hi/lo
// split (fp32-equivalent numerics): acc += Alo*Bhi + Ahi*Blo + Ahi*Bhi.
// Weights/emb pre-split in prep; h stored as hi/lo bf16 planes; c fp32.

typedef unsigned short u16;
typedef __attribute__((ext_vector_type(8))) short short8;
typedef __attribute__((ext_vector_type(4))) float floatx4;

__device__ __forceinline__ float bf2f(u16 s) {
  union { unsigned int u; float f; } v; v.u = ((unsigned int)s) << 16; return v.f;
}
__device__ __forceinline__ u16 f2bf(float x) {
  union { float f; unsigned int u; } v; v.f = x;
  unsigned int r = (v.u + 0x7FFFu + ((v.u >> 16) & 1u)) >> 16;
  return (u16)r;
}
__device__ __forceinline__ void split2(float x, u16* hi, u16* lo) {
  u16 h = f2bf(x);
  *hi = h;
  *lo = f2bf(x - bf2f(h));
}
__device__ __forceinline__ float sigm(float x) { return 1.0f / (1.0f + expf(-x)); }

// ---------------------------------------------------------------- prep ------
__global__ __launch_bounds__(256) void prep_m(
    const float* __restrict__ e_wih, const float* __restrict__ e_whh,
    const float* __restrict__ e_bih, const float* __restrict__ e_bhh,
    const float* __restrict__ d_wih, const float* __restrict__ d_whh,
    const float* __restrict__ d_bih, const float* __restrict__ d_bhh,
    const float* __restrict__ emb, const float* __restrict__ dec_emb,
    const float* __restrict__ fc_w, const float* __restrict__ fc_b,
    u16* __restrict__ WhiE, u16* __restrict__ WloE,
    u16* __restrict__ WhiD, u16* __restrict__ WloD,
    float* __restrict__ bcE, float* __restrict__ bcD,
    u16* __restrict__ eHiE, u16* __restrict__ eLoE,
    u16* __restrict__ eHiD, u16* __restrict__ eLoD,
    float* __restrict__ fwT, float* __restrict__ fcb,
    u16* __restrict__ hHi, u16* __restrict__ hLo,
    float* __restrict__ c, float* __restrict__ out) {
  int idx0 = blockIdx.x * blockDim.x + threadIdx.x;
  int stride = gridDim.x * blockDim.x;
  for (int i = idx0; i < 2048 * 768; i += stride) {
    int rr = i / 768, k = i - rr * 768;
    int j = rr >> 2, g = rr & 3;
    int orig = g * 512 + j;  // reference gate order i,f,g,o
    float we = (k < 256) ? e_wih[orig * 256 + k] : e_whh[orig * 512 + (k - 256)];
    float wd = (k < 256) ? d_wih[orig * 256 + k] : d_whh[orig * 512 + (k - 256)];
    split2(we, &WhiE[i], &WloE[i]);
    split2(wd, &WhiD[i], &WloD[i]);
  }
  for (int i = idx0; i < 2048; i += stride) {
    int j = i >> 2, g = i & 3, orig = g * 512 + j;
    bcE[i] = e_bih[orig] + e_bhh[orig];
    bcD[i] = d_bih[orig] + d_bhh[orig];
  }
  for (int i = idx0; i < 128 * 256; i += stride) {
    split2(emb[i], &eHiE[i], &eLoE[i]);
    split2(dec_emb[i], &eHiD[i], &eLoD[i]);
  }
  for (int i = idx0; i < 128 * 512; i += stride) {
    int v = i >> 9, k = i & 511;
    fwT[k * 128 + v] = fc_w[i];
  }
  for (int i = idx0; i < 128; i += stride) fcb[i] = fc_b[i];
  for (int i = idx0; i < 1024 * 512; i += stride) {
    hHi[i] = 0; hLo[i] = 0; c[i] = 0.0f;
  }
  for (int i = idx0; i < 1024 * 128; i += stride)
    out[(i >> 7) * 16384 + (i & 127)] = 0.0f;  // out[:,0,:] = 0
}

// ------------------------------------------------------------ lstm step -----
// grid (32,16): bx -> n0 (interleaved gate cols), by -> m0 (batch). 256 thr.
// 64x64 tile, 4 waves, 2x2 MFMA 16x16x32, 3-term hi/lo split.
__global__ __launch_bounds__(256) void lstm_step_m(
    const u16* __restrict__ eHi, const u16* __restrict__ eLo,  // (V,256)
    const int* __restrict__ idx, int t,
    const u16* __restrict__ Whi, const u16* __restrict__ Wlo,  // (2048,768)
    const float* __restrict__ bc,                              // (2048)
    const u16* __restrict__ hHi_in, const u16* __restrict__ hLo_in,
    u16* __restrict__ hHi_out, u16* __restrict__ hLo_out,
    float* __restrict__ c) {
  __shared__ __align__(16) unsigned char smem[20480];  // 4 tiles, stride 40 sh
  __shared__ int sidx[64];
  short* sAhi = (short*)(smem);
  short* sAlo = (short*)(smem + 5120);
  short* sBhi = (short*)(smem + 10240);
  short* sBlo = (short*)(smem + 15360);
  const int tid = threadIdx.x;
  const int m0 = blockIdx.y * 64;
  const int n0 = blockIdx.x * 64;

  if (tid < 64) sidx[tid] = idx[(m0 + tid) * 128 + t];
  __syncthreads();

  // staging: thread stages row rs = tid>>2, 8 els at qo = (tid&3)*8
  const int rs = tid >> 2;
  const int qo = (tid & 3) * 8;
  const int so = rs * 40 + qo;  // LDS short offset
  const u16* aHiE = eHi + sidx[rs] * 256 + qo;
  const u16* aLoE = eLo + sidx[rs] * 256 + qo;
  const u16* aHiH = hHi_in + (m0 + rs) * 512 + qo;
  const u16* aLoH = hLo_in + (m0 + rs) * 512 + qo;
  const u16* bHi = Whi + (n0 + rs) * 768 + qo;
  const u16* bLo = Wlo + (n0 + rs) * 768 + qo;

  const int lane = tid & 63;
  const int wv = tid >> 6;
  const int wm = wv & 1, wn = wv >> 1;
  const int lr = lane & 15, lq = lane >> 4;
  const int ra0 = wm * 32 + lr, ra1 = ra0 + 16;
  const int rb0 = wn * 32 + lr, rb1 = rb0 + 16;
  const int oa0 = ra0 * 40 + lq * 8, oa1 = ra1 * 40 + lq * 8;
  const int ob0 = rb0 * 40 + lq * 8, ob1 = rb1 * 40 + lq * 8;

  floatx4 acc00 = {0.f, 0.f, 0.f, 0.f}, acc01 = {0.f, 0.f, 0.f, 0.f};
  floatx4 acc10 = {0.f, 0.f, 0.f, 0.f}, acc11 = {0.f, 0.f, 0.f, 0.f};

  // 1-deep prefetch (kk=0 is emb region)
  short8 vah = *(const short8*)aHiE;
  short8 val = *(const short8*)aLoE;
  short8 vbh = *(const short8*)bHi;
  short8 vbl = *(const short8*)bLo;

  for (int kk = 0; kk < 24; ++kk) {
    *(short8*)&sAhi[so] = vah;
    *(short8*)&sAlo[so] = val;
    *(short8*)&sBhi[so] = vbh;
    *(short8*)&sBlo[so] = vbl;
    __syncthreads();
    if (kk < 23) {
      const int k1 = (kk + 1) * 32;
      if (k1 < 256) {
        vah = *(const short8*)(aHiE + k1);
        val = *(const short8*)(aLoE + k1);
      } else {
        vah = *(const short8*)(aHiH + (k1 - 256));
        val = *(const short8*)(aLoH + (k1 - 256));
      }
      vbh = *(const short8*)(bHi + k1);
      vbl = *(const short8*)(bLo + k1);
    }
    short8 ah0 = *(const short8*)&sAhi[oa0];
    short8 ah1 = *(const short8*)&sAhi[oa1];
    short8 al0 = *(const short8*)&sAlo[oa0];
    short8 al1 = *(const short8*)&sAlo[oa1];
    short8 bh0 = *(const short8*)&sBhi[ob0];
    short8 bh1 = *(const short8*)&sBhi[ob1];
    short8 bl0 = *(const short8*)&sBlo[ob0];
    short8 bl1 = *(const short8*)&sBlo[ob1];
    acc00 = __builtin_amdgcn_mfma_f32_16x16x32_bf16(al0, bh0, acc00, 0, 0, 0);
    acc00 = __builtin_amdgcn_mfma_f32_16x16x32_bf16(ah0, bl0, acc00, 0, 0, 0);
    acc00 = __builtin_amdgcn_mfma_f32_16x16x32_bf16(ah0, bh0, acc00, 0, 0, 0);
    acc01 = __builtin_amdgcn_mfma_f32_16x16x32_bf16(al0, bh1, acc01, 0, 0, 0);
    acc01 = __builtin_amdgcn_mfma_f32_16x16x32_bf16(ah0, bl1, acc01, 0, 0, 0);
    acc01 = __builtin_amdgcn_mfma_f32_16x16x32_bf16(ah0, bh1, acc01, 0, 0, 0);
    acc10 = __builtin_amdgcn_mfma_f32_16x16x32_bf16(al1, bh0, acc10, 0, 0, 0);
    acc10 = __builtin_amdgcn_mfma_f32_16x16x32_bf16(ah1, bl0, acc10, 0, 0, 0);
    acc10 = __builtin_amdgcn_mfma_f32_16x16x32_bf16(ah1, bh0, acc10, 0, 0, 0);
    acc11 = __builtin_amdgcn_mfma_f32_16x16x32_bf16(al1, bh1, acc11, 0, 0, 0);
    acc11 = __builtin_amdgcn_mfma_f32_16x16x32_bf16(ah1, bl1, acc11, 0, 0, 0);
    acc11 = __builtin_amdgcn_mfma_f32_16x16x32_bf16(ah1, bh1, acc11, 0, 0, 0);
    __syncthreads();
  }

  // gates -> LDS fp32 (stride 68 floats; reuses the tile memory)
  float* gl = (float*)smem;
  const int rowb = wm * 32 + lq * 4;
  const int colb = wn * 32 + lr;
#pragma unroll
  for (int j = 0; j < 4; ++j) {
    gl[(rowb + j) * 68 + colb] = acc00[j];
    gl[(rowb + j) * 68 + colb + 16] = acc01[j];
    gl[(rowb + 16 + j) * 68 + colb] = acc10[j];
    gl[(rowb + 16 + j) * 68 + colb + 16] = acc11[j];
  }
  __syncthreads();

  // fused LSTM cell: 64 rows x 16 units per block
#pragma unroll
  for (int ii = 0; ii < 4; ++ii) {
    int pp = ii * 256 + tid;
    int row = pp >> 4;
    int u = pp & 15;
    const float* gp = gl + row * 68 + u * 4;
    float gi = gp[0], gf = gp[1], gg = gp[2], go = gp[3];
    const float* bp = bc + n0 + u * 4;
    gi += bp[0]; gf += bp[1]; gg += bp[2]; go += bp[3];
    int gb = m0 + row;
    int gu = (n0 >> 2) + u;
    int ci = gb * 512 + gu;
    float cold = c[ci];
    float cn = sigm(gf) * cold + sigm(gi) * tanhf(gg);
    c[ci] = cn;
    float h = sigm(go) * tanhf(cn);
    u16 hi, lo;
    split2(h, &hi, &lo);
    hHi_out[ci] = hi;
    hLo_out[ci] = lo;
  }
}

// --------------------------------------------------------------- fc step ----
// out[:, t+1, :] = h @ fc_w^T + fc_b (h = hi + lo planes). grid (128), 256 thr.
__global__ __launch_bounds__(256) void fc_step_v(
    const u16* __restrict__ hHi, const u16* __restrict__ hLo,  // (1024,512)
    const float* __restrict__ fwT,  // (512,128) = fc_w^T
    const float* __restrict__ fcb,  // (128)
    float* __restrict__ out, int t) {
  __shared__ float smH[4096];  // 8 rows x 512; reused as reduce scratch
  const int tid = threadIdx.x;
  const int b0 = blockIdx.x * 8;
  {
    int o = b0 * 512 + tid * 16;
    short8 vh = *(const short8*)(hHi + o);
    short8 vl = *(const short8*)(hLo + o);
    short8 vh2 = *(const short8*)(hHi + o + 8);
    short8 vl2 = *(const short8*)(hLo + o + 8);
    float* d = &smH[tid * 16];
#pragma unroll
    for (int j = 0; j < 8; ++j) d[j] = bf2f((u16)vh[j]) + bf2f((u16)vl[j]);
#pragma unroll
    for (int j = 0; j < 8; ++j) d[8 + j] = bf2f((u16)vh2[j]) + bf2f((u16)vl2[j]);
  }
  __syncthreads();

  const int v = tid & 127;
  const int half = tid >> 7;
  float acc[8];
#pragma unroll
  for (int r0 = 0; r0 < 8; ++r0) acc[r0] = 0.0f;
  const int kbase = half * 256;
  for (int k = kbase; k < kbase + 256; ++k) {
    float w = fwT[k * 128 + v];
#pragma unroll
    for (int r0 = 0; r0 < 8; ++r0) acc[r0] += smH[r0 * 512 + k] * w;
  }
  __syncthreads();
  float* red = smH;
#pragma unroll
  for (int r0 = 0; r0 < 8; ++r0) red[half * 1024 + r0 * 128 + v] = acc[r0];
  __syncthreads();
  if (half == 0) {
    float bias = fcb[v];
#pragma unroll
    for (int r0 = 0; r0 < 8; ++r0) {
      float sum = red[r0 * 128 + v] + red[1024 + r0 * 128 + v] + bias;
      out[(b0 + r0) * 16384 + (t + 1) * 128 + v] = sum;
    }
  }
}

// ---------------------------------------------------------------- launch ----
extern "C" void kernel_launch(void* const* d_in, const int* in_sizes, int n_in,
                              void* d_out, int out_size, void* d_ws, size_t ws_size,
                              hipStream_t stream) {
  const int* src = (const int*)d_in[0];
  const int* tgt = (const int*)d_in[1];
  const float* emb = (const float*)d_in[2];
  const float* dec_emb = (const float*)d_in[3];
  const float* e_wih = (const float*)d_in[4];
  const float* e_whh = (const float*)d_in[5];
  const float* e_bih = (const float*)d_in[6];
  const float* e_bhh = (const float*)d_in[7];
  const float* d_wih = (const float*)d_in[8];
  const float* d_whh = (const float*)d_in[9];
  const float* d_bih = (const float*)d_in[10];
  const float* d_bhh = (const float*)d_in[11];
  const float* fc_w = (const float*)d_in[12];
  const float* fc_b = (const float*)d_in[13];
  float* out = (float*)d_out;

  char* ws = (char*)d_ws;
  u16* WhiE = (u16*)(ws + 0);             // 3,145,728
  u16* WloE = (u16*)(ws + 3145728);       // 3,145,728
  u16* WhiD = (u16*)(ws + 6291456);       // 3,145,728
  u16* WloD = (u16*)(ws + 9437184);       // 3,145,728
  float* bcE = (float*)(ws + 12582912);   // 8,192
  float* bcD = (float*)(ws + 12591104);   // 8,192
  u16* eHiE = (u16*)(ws + 12599296);      // 65,536
  u16* eLoE = (u16*)(ws + 12664832);      // 65,536
  u16* eHiD = (u16*)(ws + 12730368);      // 65,536
  u16* eLoD = (u16*)(ws + 12795904);      // 65,536
  float* fwT = (float*)(ws + 12861440);   // 262,144
  float* fcb = (float*)(ws + 13123584);   // 512
  u16* hHiA = (u16*)(ws + 13124096);      // 1,048,576
  u16* hLoA = (u16*)(ws + 14172672);      // 1,048,576
  u16* hHiB = (u16*)(ws + 15221248);      // 1,048,576
  u16* hLoB = (u16*)(ws + 16269824);      // 1,048,576
  float* cbuf = (float*)(ws + 17318400);  // 2,097,152  (total ~18.5 MB)

  prep_m<<<1024, 256, 0, stream>>>(e_wih, e_whh, e_bih, e_bhh,
                                   d_wih, d_whh, d_bih, d_bhh,
                                   emb, dec_emb, fc_w, fc_b,
                                   WhiE, WloE, WhiD, WloD, bcE, bcD,
                                   eHiE, eLoE, eHiD, eLoD, fwT, fcb,
                                   hHiA, hLoA, cbuf, out);

  dim3 gstep(32, 16);
  const u16* hHi_in = hHiA; const u16* hLo_in = hLoA;
  u16* hHi_out = hHiB; u16* hLo_out = hLoB;
  for (int t = 0; t < 128; ++t) {
    lstm_step_m<<<gstep, 256, 0, stream>>>(eHiE, eLoE, src, t, WhiE, WloE, bcE,
                                           hHi_in, hLo_in, hHi_out, hLo_out, cbuf);
    const u16* th = hHi_out; hHi_out = (u16*)hHi_in; hHi_in = th;
    const u16* tl = hLo_out; hLo_out = (u16*)hLo_in; hLo_in = tl;
  }
  for (int t = 0; t < 127; ++t) {
    lstm_step_m<<<gstep, 256, 0, stream>>>(eHiD, eLoD, tgt, t, WhiD, WloD, bcD,
                                           hHi_in, hLo_in, hHi_out, hLo_out, cbuf);
    const u16* th = hHi_out; hHi_out = (u16*)hHi_in; hHi_in = th;
    const u16* tl = hLo_out; hLo_out = (u16*)hLo_in; hLo_in = tl;
    fc_step_v<<<128, 256, 0, stream>>>(hHi_in, hLo_in, fwT, fcb, out, t);
  }
}